// Round 28
// baseline (95.059 us; speedup 1.0000x reference)
//
#include <hip/hip_runtime.h>
#include <hip/hip_bf16.h>

#define SCOPE 63
#define BT 256
#define RPB 64                      // rows per block (halved: occupancy lever)
#define TILE_ELEMS (RPB * SCOPE)    // 4032 floats = 16128 B

typedef __attribute__((ext_vector_type(8))) __bf16 v8bf;
typedef __attribute__((ext_vector_type(4))) float f32x4;

// async global->LDS, 16B per lane; LDS dest is wave-uniform base + lane*16
#define GLL(gp, lp) __builtin_amdgcn_global_load_lds(                         \
    (const __attribute__((address_space(1))) void*)(gp),                      \
    (__attribute__((address_space(3))) void*)(lp), 16, 0, 0)

// ws layout: [0,256) g as float[63]; [256, 8448) Bhi bf16[4096];
//            [8448, 16640) Blo bf16[4096]   (fragment order [nt][kt][lane][8])
#define WS_BHI_OFF 256
#define WS_BLO_OFF 8448

// ---------------------------------------------------------------------------
// Kernel 1 (one-time): inverse filter g = IFFT(1/FFT(delta-f)) in fp64, plus
// the fragment-ordered bf16 hi/lo circulant-B arrays into d_ws.
// ---------------------------------------------------------------------------
__global__ void compute_inverse_filter(const float* __restrict__ f,
                                       float* __restrict__ ws) {
    __shared__ double hre[SCOPE];
    __shared__ double him[SCOPE];
    __shared__ float gsm[SCOPE];
    const double TWO_PI = 6.283185307179586476925286766559;
    int t = threadIdx.x;
    if (t < SCOPE) {
        double re = 0.0, im = 0.0;
        for (int n = 0; n < SCOPE; ++n) {
            double x = (n == 0 ? 1.0 : 0.0) - (double)f[n];
            double ang = -TWO_PI * (double)(t * n) / (double)SCOPE;
            re += x * cos(ang);
            im += x * sin(ang);
        }
        double d = re * re + im * im;
        hre[t] = re / d;
        him[t] = -im / d;
    }
    __syncthreads();
    if (t < SCOPE) {
        double acc = 0.0;
        for (int k = 0; k < SCOPE; ++k) {
            double ang = TWO_PI * (double)(k * t) / (double)SCOPE;
            acc += hre[k] * cos(ang) - him[k] * sin(ang);
        }
        float gv = (float)(acc / (double)SCOPE);
        ws[t] = gv;          // keep g in ws[0..63)
        gsm[t] = gv;
    }
    __syncthreads();
    // ---- build B fragments in ws (block-invariant, built once ever) ----
    __bf16* Bhi = (__bf16*)((char*)ws + WS_BHI_OFF);
    __bf16* Blo = (__bf16*)((char*)ws + WS_BLO_OFF);
    for (int fidx = t; fidx < 4096; fidx += blockDim.x) {
        const int j  = fidx & 7;
        const int fl = (fidx >> 3) & 63;
        const int kt = (fidx >> 9) & 1;
        const int nt = fidx >> 10;
        const int k  = 8 * (fl >> 4) + j + 32 * kt;
        const int n  = 16 * nt + (fl & 15);
        float v = (k < SCOPE && n < SCOPE) ? gsm[(n - k + SCOPE) % SCOPE] : 0.0f;
        __bf16 h = (__bf16)v;
        Bhi[fidx] = h;
        Blo[fidx] = (__bf16)(v - (float)h);
    }
}

// ---------------------------------------------------------------------------
// Kernel 2: circulant matmul via MFMA (r19 math, verified absmax 0.03125).
//   OUT = Ahi*Bhi + Ahi*Blo + Alo*Bhi; K,N padded to 64 with zeros.
// r28 change vs r27: 64-row tiles (16.2 KB LDS) -> 8 blocks/CU (thread-slot
// max, was 4 at 32.3 KB). Wave w owns rows 16w..16w+15 (one M-tile, 24 MFMA).
// B-fragments in global ws (L2 broadcast); GLL staging; 2 barriers.
// ---------------------------------------------------------------------------
__global__ void __launch_bounds__(BT)
circ_conv_kernel(const float* __restrict__ A,
                 const float* __restrict__ WS,
                 float* __restrict__ O) {
    __shared__ __align__(16) float tile[TILE_ELEMS + 16];  // +pad for k-overread

    const int tid = threadIdx.x;
    const int w   = tid >> 6;        // wave in block
    const int l   = tid & 63;        // lane in wave
    const int c   = l & 15;          // fragment column index
    const int q   = l >> 4;          // fragment k-group / row-group

    const long long row0 = (long long)blockIdx.x * RPB;
    const float* __restrict__ src = A + row0 * SCOPE;
    float* __restrict__ dst       = O + row0 * SCOPE;

    // ---- stage 64 rows (1008 float4) via async global->LDS ----
    const float4* src4 = (const float4*)src;
    float4* w4 = (float4*)tile;
#pragma unroll
    for (int it = 0; it < 3; ++it)
        GLL(src4 + it * 256 + tid, w4 + it * 256 + tid);
    if (tid < 240)
        GLL(src4 + 768 + tid, w4 + 768 + tid);
    if (tid < 16) tile[TILE_ELEMS + tid] = 0.0f;   // zero k-overread pad

    // ---- B fragments: global, identical across blocks -> L2 broadcast ----
    const v8bf* BH = (const v8bf*)((const char*)WS + WS_BHI_OFF);
    const v8bf* BL = (const v8bf*)((const char*)WS + WS_BLO_OFF);
    v8bf bh[4][2], bl[4][2];
#pragma unroll
    for (int nt = 0; nt < 4; ++nt)
#pragma unroll
        for (int kt = 0; kt < 2; ++kt) {
            bh[nt][kt] = BH[(nt * 2 + kt) * 64 + l];
            bl[nt][kt] = BL[(nt * 2 + kt) * 64 + l];
        }

    __syncthreads();   // tile ready (vmcnt drained)

    // ---- A fragments: row 16w + c, 8 floats at koff = 8q + 32kt ----
    v8bf ah[2], al[2];   // [kt]
#pragma unroll
    for (int kt = 0; kt < 2; ++kt) {
        const float* ap = tile + (16 * w + c) * SCOPE + 8 * q + 32 * kt;
#pragma unroll
        for (int j = 0; j < 8; ++j) {
            float v = ap[j];             // k=63 overread: pad/next row, *0
            __bf16 h = (__bf16)v;
            ah[kt][j] = h;
            al[kt][j] = (__bf16)(v - (float)h);
        }
    }

    // ---- 4 N-tiles x (2 kt x 3 passes) = 24 MFMA ----
#pragma unroll
    for (int nt = 0; nt < 4; ++nt) {
        f32x4 acc = {0.f, 0.f, 0.f, 0.f};
#pragma unroll
        for (int kt = 0; kt < 2; ++kt) {
            acc = __builtin_amdgcn_mfma_f32_16x16x32_bf16(ah[kt], bh[nt][kt], acc, 0, 0, 0);
            acc = __builtin_amdgcn_mfma_f32_16x16x32_bf16(ah[kt], bl[nt][kt], acc, 0, 0, 0);
            acc = __builtin_amdgcn_mfma_f32_16x16x32_bf16(al[kt], bh[nt][kt], acc, 0, 0, 0);
        }
        // C: col = 16nt + c, rows 16w + 4q + i (own rows)
        const int col = 16 * nt + c;
        if (col < SCOPE) {
            float* cp = tile + (16 * w + 4 * q) * SCOPE + col;
#pragma unroll
            for (int i = 0; i < 4; ++i)
                cp[i * SCOPE] = acc[i];
        }
    }

    __syncthreads();   // all outputs in tile

    // ---- coalesced float4 store ----
    float4* dst4 = (float4*)dst;
#pragma unroll
    for (int it = 0; it < 3; ++it)
        dst4[it * 256 + tid] = w4[it * 256 + tid];
    if (tid < 240)
        dst4[768 + tid] = w4[768 + tid];
}

// ---------------------------------------------------------------------------
extern "C" void kernel_launch(void* const* d_in, const int* in_sizes, int n_in,
                              void* d_out, int out_size, void* d_ws, size_t ws_size,
                              hipStream_t stream) {
    const float* activations = (const float*)d_in[0];
    const float* filt        = (const float*)d_in[1];
    float* out               = (float*)d_out;
    float* ws                = (float*)d_ws;   // g + B-fragment arrays (~17 KB)

    hipLaunchKernelGGL(compute_inverse_filter, dim3(1), dim3(BT), 0, stream,
                       filt, ws);

    const long long total = (long long)in_sizes[0];
    const long long rows  = total / SCOPE;          // 524288
    const int blocks      = (int)(rows / RPB);      // 8192, exact

    hipLaunchKernelGGL(circ_conv_kernel, dim3(blocks), dim3(BT), 0,
                       stream, activations, ws, out);
}

// Round 29
// 57.200 us; speedup vs baseline: 1.6619x; 1.6619x over previous
//
#include <hip/hip_runtime.h>
#include <hip/hip_bf16.h>

#define SCOPE 63
#define BT 256
#define RPB 64                      // rows per block
#define TILE_ELEMS (RPB * SCOPE)    // 4032 floats = 16128 B

typedef __attribute__((ext_vector_type(8))) __bf16 v8bf;
typedef __attribute__((ext_vector_type(4))) float f32x4;

// async global->LDS, 16B per lane; LDS dest is wave-uniform base + lane*16
#define GLL(gp, lp) __builtin_amdgcn_global_load_lds(                         \
    (const __attribute__((address_space(1))) void*)(gp),                      \
    (__attribute__((address_space(3))) void*)(lp), 16, 0, 0)

// ws layout: [0,256) g as float[63]; [256, 8448) Bhi bf16[4096];
//            [8448, 16640) Blo bf16[4096]   (fragment order [nt][kt][lane][8])
#define WS_BHI_OFF 256
#define WS_BLO_OFF 8448

// ---------------------------------------------------------------------------
// Kernel 1 (one-time): g = IFFT(1/FFT(delta-f)) in fp64 + bf16 hi/lo B-frags.
// r29 fix: all DFT angles are 2*pi*((t*n) mod 63)/63 -> only 63 distinct
// twiddles. Compute the 63 double sincos ONCE (parallel, 1/thread), then both
// DFT loops are table-lookup FMAs. Was ~126 serial double sincos per thread
// (~19 us serialized before the main kernel); now ~2 us.
// ---------------------------------------------------------------------------
__global__ void compute_inverse_filter(const float* __restrict__ f,
                                       float* __restrict__ ws) {
    __shared__ double cd[SCOPE];   // cos(-2*pi*m/63)
    __shared__ double sd[SCOPE];   // sin(-2*pi*m/63)
    __shared__ double hre[SCOPE];
    __shared__ double him[SCOPE];
    __shared__ float gsm[SCOPE];
    const double TWO_PI = 6.283185307179586476925286766559;
    int t = threadIdx.x;

    if (t < SCOPE) {
        double ang = -TWO_PI * (double)t / (double)SCOPE;
        cd[t] = cos(ang);
        sd[t] = sin(ang);
    }
    __syncthreads();

    if (t < SCOPE) {
        // FF[t] = sum_n (delta[n] - f[n]) * exp(-i 2 pi t n / 63)
        double re = 0.0, im = 0.0;
        for (int n = 0; n < SCOPE; ++n) {
            double x = (n == 0 ? 1.0 : 0.0) - (double)f[n];
            int m = (t * n) % SCOPE;
            re += x * cd[m];
            im += x * sd[m];
        }
        double d = re * re + im * im;
        hre[t] = re / d;
        him[t] = -im / d;
    }
    __syncthreads();

    if (t < SCOPE) {
        // g[t] = (1/63) sum_k Re(H[k] * exp(+i 2 pi k t / 63))
        //      = (1/63) sum_k (hre[k]*cd[m] + him[k]*sd[m]),  m = (k*t)%63
        // (cos(+a)=cd, sin(+a)=-sd)
        double acc = 0.0;
        for (int k = 0; k < SCOPE; ++k) {
            int m = (k * t) % SCOPE;
            acc += hre[k] * cd[m] + him[k] * sd[m];
        }
        float gv = (float)(acc / (double)SCOPE);
        ws[t] = gv;
        gsm[t] = gv;
    }
    __syncthreads();

    // ---- build B fragments in ws (block-invariant, built once ever) ----
    __bf16* Bhi = (__bf16*)((char*)ws + WS_BHI_OFF);
    __bf16* Blo = (__bf16*)((char*)ws + WS_BLO_OFF);
    for (int fidx = t; fidx < 4096; fidx += blockDim.x) {
        const int j  = fidx & 7;
        const int fl = (fidx >> 3) & 63;
        const int kt = (fidx >> 9) & 1;
        const int nt = fidx >> 10;
        const int k  = 8 * (fl >> 4) + j + 32 * kt;
        const int n  = 16 * nt + (fl & 15);
        float v = (k < SCOPE && n < SCOPE) ? gsm[(n - k + SCOPE) % SCOPE] : 0.0f;
        __bf16 h = (__bf16)v;
        Bhi[fidx] = h;
        Blo[fidx] = (__bf16)(v - (float)h);
    }
}

// ---------------------------------------------------------------------------
// Kernel 2 (unchanged from r28, 76 us steady): circulant matmul via MFMA.
//   OUT = Ahi*Bhi + Ahi*Blo + Alo*Bhi; K,N padded to 64 with zeros.
// 64-row tiles (16.2 KB LDS) -> 8 blocks/CU; wave w owns rows 16w..16w+15;
// B-fragments in global ws (L2 broadcast); GLL staging; 2 barriers.
// ---------------------------------------------------------------------------
__global__ void __launch_bounds__(BT)
circ_conv_kernel(const float* __restrict__ A,
                 const float* __restrict__ WS,
                 float* __restrict__ O) {
    __shared__ __align__(16) float tile[TILE_ELEMS + 16];  // +pad for k-overread

    const int tid = threadIdx.x;
    const int w   = tid >> 6;        // wave in block
    const int l   = tid & 63;        // lane in wave
    const int c   = l & 15;          // fragment column index
    const int q   = l >> 4;          // fragment k-group / row-group

    const long long row0 = (long long)blockIdx.x * RPB;
    const float* __restrict__ src = A + row0 * SCOPE;
    float* __restrict__ dst       = O + row0 * SCOPE;

    // ---- stage 64 rows (1008 float4) via async global->LDS ----
    const float4* src4 = (const float4*)src;
    float4* w4 = (float4*)tile;
#pragma unroll
    for (int it = 0; it < 3; ++it)
        GLL(src4 + it * 256 + tid, w4 + it * 256 + tid);
    if (tid < 240)
        GLL(src4 + 768 + tid, w4 + 768 + tid);
    if (tid < 16) tile[TILE_ELEMS + tid] = 0.0f;   // zero k-overread pad

    // ---- B fragments: global, identical across blocks -> L2 broadcast ----
    const v8bf* BH = (const v8bf*)((const char*)WS + WS_BHI_OFF);
    const v8bf* BL = (const v8bf*)((const char*)WS + WS_BLO_OFF);
    v8bf bh[4][2], bl[4][2];
#pragma unroll
    for (int nt = 0; nt < 4; ++nt)
#pragma unroll
        for (int kt = 0; kt < 2; ++kt) {
            bh[nt][kt] = BH[(nt * 2 + kt) * 64 + l];
            bl[nt][kt] = BL[(nt * 2 + kt) * 64 + l];
        }

    __syncthreads();   // tile ready (vmcnt drained)

    // ---- A fragments: row 16w + c, 8 floats at koff = 8q + 32kt ----
    v8bf ah[2], al[2];   // [kt]
#pragma unroll
    for (int kt = 0; kt < 2; ++kt) {
        const float* ap = tile + (16 * w + c) * SCOPE + 8 * q + 32 * kt;
#pragma unroll
        for (int j = 0; j < 8; ++j) {
            float v = ap[j];             // k=63 overread: pad/next row, *0
            __bf16 h = (__bf16)v;
            ah[kt][j] = h;
            al[kt][j] = (__bf16)(v - (float)h);
        }
    }

    // ---- 4 N-tiles x (2 kt x 3 passes) = 24 MFMA ----
#pragma unroll
    for (int nt = 0; nt < 4; ++nt) {
        f32x4 acc = {0.f, 0.f, 0.f, 0.f};
#pragma unroll
        for (int kt = 0; kt < 2; ++kt) {
            acc = __builtin_amdgcn_mfma_f32_16x16x32_bf16(ah[kt], bh[nt][kt], acc, 0, 0, 0);
            acc = __builtin_amdgcn_mfma_f32_16x16x32_bf16(ah[kt], bl[nt][kt], acc, 0, 0, 0);
            acc = __builtin_amdgcn_mfma_f32_16x16x32_bf16(al[kt], bh[nt][kt], acc, 0, 0, 0);
        }
        // C: col = 16nt + c, rows 16w + 4q + i (own rows)
        const int col = 16 * nt + c;
        if (col < SCOPE) {
            float* cp = tile + (16 * w + 4 * q) * SCOPE + col;
#pragma unroll
            for (int i = 0; i < 4; ++i)
                cp[i * SCOPE] = acc[i];
        }
    }

    __syncthreads();   // all outputs in tile

    // ---- coalesced float4 store ----
    float4* dst4 = (float4*)dst;
#pragma unroll
    for (int it = 0; it < 3; ++it)
        dst4[it * 256 + tid] = w4[it * 256 + tid];
    if (tid < 240)
        dst4[768 + tid] = w4[768 + tid];
}

// ---------------------------------------------------------------------------
extern "C" void kernel_launch(void* const* d_in, const int* in_sizes, int n_in,
                              void* d_out, int out_size, void* d_ws, size_t ws_size,
                              hipStream_t stream) {
    const float* activations = (const float*)d_in[0];
    const float* filt        = (const float*)d_in[1];
    float* out               = (float*)d_out;
    float* ws                = (float*)d_ws;   // g + B-fragment arrays (~17 KB)

    hipLaunchKernelGGL(compute_inverse_filter, dim3(1), dim3(BT), 0, stream,
                       filt, ws);

    const long long total = (long long)in_sizes[0];
    const long long rows  = total / SCOPE;          // 524288
    const int blocks      = (int)(rows / RPB);      // 8192, exact

    hipLaunchKernelGGL(circ_conv_kernel, dim3(blocks), dim3(BT), 0,
                       stream, activations, ws, out);
}